// Round 7
// baseline (136.863 us; speedup 1.0000x reference)
//
#include <hip/hip_runtime.h>
#include <math.h>

// ---------------------------------------------------------------------------
// EntRNN R7: single fused GEMM+scan kernel with decoupled lookback (agent-
// scope atomics), replacing R6's xf round-trip + scan_final kernel.
// K-loop identical to R6 (verified): A staged once to LDS (f16, xor-swizzle),
// W k-slices register-pipelined, MFMA 32x32x16_f16.
// After local scan, block publishes (Aprod,Hlocal); waits on predecessor
// flags (parallel, one per thread); folds summaries; replays chunk from LDS;
// writes fp32 out. 512 blocks @ 2/CU = all co-resident -> no deadlock.
// B=8, T=4096, D=256.
// ---------------------------------------------------------------------------

typedef _Float16 f16x8 __attribute__((ext_vector_type(8)));
typedef float f32x4 __attribute__((ext_vector_type(4)));
typedef float f32x16 __attribute__((ext_vector_type(16)));

constexpr int B_ = 8, T_ = 4096, D_ = 256, K_ = 256;
constexpr int M_ = B_ * T_;          // 32768 rows
constexpr int CHUNK = 64;            // rows per block == scan chunk
constexpr int NCH = T_ / CHUNK;      // 64 chunks per sequence
constexpr int NBLK = M_ / CHUNK;     // 512 blocks

struct alignas(4) XF { _Float16 x, f; };

__device__ __forceinline__ float fexp2(float a) { return __builtin_amdgcn_exp2f(a); }
__device__ __forceinline__ float frcp(float a) { return __builtin_amdgcn_rcpf(a); }
constexpr float L2E = 1.4426950408889634f;

__device__ __forceinline__ float fast_sigmoid(float z) {
  return frcp(1.f + fexp2(-z * L2E));
}
__device__ __forceinline__ float fast_tanh(float z) {
  const float t = fexp2(-2.f * L2E * fabsf(z));
  return copysignf((1.f - t) * frcp(1.f + t), z);
}

// ---- K0: repack W fp32 -> f16, k-major chunks: g = kk*2048+(mat*4+kc)*256+n
__global__ __launch_bounds__(256) void wconv(const float* __restrict__ Win,
                                             const float* __restrict__ Wf,
                                             _Float16* __restrict__ Wh2) {
  const int t = blockIdx.x * 256 + threadIdx.x;
  const int n = t & 255;
  const int kc = (t >> 8) & 3;
  const int mat = (t >> 10) & 1;
  const int kk = t >> 11;
  const float* s = (mat ? Wf : Win) + (size_t)n * K_ + kk * 32 + kc * 8;
  f32x4 a = *(const f32x4*)s;
  f32x4 b = *(const f32x4*)(s + 4);
  f16x8 o;
  o[0] = (_Float16)a[0]; o[1] = (_Float16)a[1];
  o[2] = (_Float16)a[2]; o[3] = (_Float16)a[3];
  o[4] = (_Float16)b[0]; o[5] = (_Float16)b[1];
  o[6] = (_Float16)b[2]; o[7] = (_Float16)b[3];
  *(f16x8*)(Wh2 + (size_t)t * 8) = o;
}

// ---- K1: fused GEMM + activations + full scan (decoupled lookback) -------
// 512 blocks x 256 thr, 2 blocks/CU (LDS 64 KiB). 4 waves: mw=w>>1 (32-row
// half), nw=w&1 (128-col half). LDS: [A 32K | W-slice 32K] in K-loop,
// XF[64][256] after (union).
__global__ __launch_bounds__(256, 2) void gemm_scan(
    const float* __restrict__ A, const _Float16* __restrict__ Wh2,
    const float* __restrict__ bin, const float* __restrict__ bfv,
    const float* __restrict__ mask, unsigned long long* __restrict__ AH,
    int* __restrict__ flags, float* __restrict__ out) {
  __shared__ __align__(16) char smem[65536];
  char* ldsA = smem;            // [m(64)][swz(32)] 16B chunks, swz = kcg ^ (m&31)
  char* ldsW = smem + 32768;    // per-kk slice: [(mat*4+kc)*256 + n] 16B chunks

  const int tid = threadIdx.x;
  const int w = tid >> 6, lane = tid & 63;
  const int mw = w >> 1, nw = w & 1;
  const int nl = lane & 31, kh = lane >> 5;
  const int ml = mw * 32 + nl;
  const int g = blockIdx.x;
  const int row0b = g * CHUNK;

  f32x16 acc[2][4];
#pragma unroll
  for (int mat = 0; mat < 2; ++mat)
#pragma unroll
    for (int nt = 0; nt < 4; ++nt) acc[mat][nt] = (f32x16)(0.f);

  // ---- stage ALL of A (64 rows x 256 k) fp32->f16, xor-swizzled ----
  {
    const int am = tid >> 2;               // row 0..63
    const int ak4 = (tid & 3) * 8;         // base k-chunk (8 f16 per chunk)
    const float* agp = A + (size_t)(row0b + am) * K_ + ak4 * 8;
#pragma unroll
    for (int j = 0; j < 8; ++j) {
      const int kcg = ak4 + j;
      f32x4 lo = *(const f32x4*)(agp + j * 8);
      f32x4 hi = *(const f32x4*)(agp + j * 8 + 4);
      f16x8 t;
      t[0] = (_Float16)lo[0]; t[1] = (_Float16)lo[1];
      t[2] = (_Float16)lo[2]; t[3] = (_Float16)lo[3];
      t[4] = (_Float16)hi[0]; t[5] = (_Float16)hi[1];
      t[6] = (_Float16)hi[2]; t[7] = (_Float16)hi[3];
      *(f16x8*)(ldsA + am * 512 + ((kcg ^ (am & 31)) << 4)) = t;
    }
  }

  // ---- prologue: W slice kk=0 into regs ----
  f16x8 wreg[8];
#pragma unroll
  for (int j = 0; j < 8; ++j)
    wreg[j] = *(const f16x8*)(Wh2 + (size_t)(j * 256 + tid) * 8);

  // ---- K-loop: write slice | barrier | prefetch kk+1 | frags+MFMA | barrier
  for (int kk = 0; kk < 8; ++kk) {
#pragma unroll
    for (int j = 0; j < 8; ++j)
      *(f16x8*)(ldsW + (size_t)(j * 256 + tid) * 16) = wreg[j];
    __syncthreads();                      // slice (and, first iter, A) ready
    if (kk < 7) {
#pragma unroll
      for (int j = 0; j < 8; ++j)
        wreg[j] = *(const f16x8*)(Wh2 + (size_t)(kk + 1) * 16384 +
                                  (size_t)(j * 256 + tid) * 8);
    }
    f16x8 afr[2];
#pragma unroll
    for (int i2 = 0; i2 < 2; ++i2) {
      const int kcg = kk * 4 + i2 * 2 + kh;
      afr[i2] = *(const f16x8*)(ldsA + ml * 512 + ((kcg ^ (ml & 31)) << 4));
    }
#pragma unroll
    for (int mat = 0; mat < 2; ++mat)
#pragma unroll
      for (int nt = 0; nt < 4; ++nt) {
        const int n = nw * 128 + nt * 32 + nl;
#pragma unroll
        for (int i2 = 0; i2 < 2; ++i2) {
          const int kc = i2 * 2 + kh;
          f16x8 bfr = *(const f16x8*)(ldsW + (size_t)((mat * 4 + kc) * 256 + n) * 16);
          acc[mat][nt] = __builtin_amdgcn_mfma_f32_32x32x16_f16(
              afr[i2], bfr, acc[mat][nt], 0, 0, 0);
        }
      }
    __syncthreads();                      // slice consumed (next write / XF safe)
  }

  // ---- epilogue: bias + mask + activations -> XF in LDS only ----
  float bx[4], bf[4];
#pragma unroll
  for (int nt = 0; nt < 4; ++nt) {
    const int col = nw * 128 + nt * 32 + nl;
    bx[nt] = bin[col];
    bf[nt] = bfv[col];
  }
  float madd[16];
  int rowl[16];
#pragma unroll
  for (int reg = 0; reg < 16; ++reg) {
    const int rl = mw * 32 + (reg & 3) + 8 * (reg >> 2) + 4 * kh;
    rowl[reg] = rl;
    madd[reg] = 10000.f * mask[row0b + rl];
  }
#pragma unroll
  for (int nt = 0; nt < 4; ++nt) {
    const int col = nw * 128 + nt * 32 + nl;
#pragma unroll
    for (int reg = 0; reg < 16; ++reg) {
      const float zx = acc[0][nt][reg] + bx[nt];
      const float zf = acc[1][nt][reg] + bf[nt] + madd[reg];
      XF v;
      v.x = (_Float16)fast_tanh(zx);
      v.f = (_Float16)fast_sigmoid(zf);
      *(XF*)(smem + ((size_t)rowl[reg] * D_ + col) * 4) = v;
    }
  }
  __syncthreads();

  // ---- local chunk scan: thread d scans 64 t from LDS ----
  const int d = tid;
  {
    float Aa = 1.f, h = 0.f;
#pragma unroll 8
    for (int t = 0; t < CHUNK; ++t) {
      const XF v = *(const XF*)(smem + ((size_t)t * D_ + d) * 4);
      const float f = (float)v.f;
      const float a = 1.f - f;
      h = f * (float)v.x + a * h;
      Aa *= a;
    }
    union { float f2[2]; unsigned long long u; } pk;
    pk.f2[0] = Aa; pk.f2[1] = h;
    __hip_atomic_store(AH + (size_t)g * D_ + d, pk.u, __ATOMIC_RELAXED,
                       __HIP_MEMORY_SCOPE_AGENT);
  }
  __syncthreads();   // all waves' summary stores drained (vmcnt) at barrier
  if (tid == 0)
    __hip_atomic_store(flags + g, 1, __ATOMIC_RELEASE, __HIP_MEMORY_SCOPE_AGENT);

  // ---- lookback: wait on predecessor flags (parallel), fold summaries ----
  const int b = g >> 6, c = g & 63;
  const int s0 = b << 6;
  if (tid < c) {
    while (__hip_atomic_load(flags + s0 + tid, __ATOMIC_ACQUIRE,
                             __HIP_MEMORY_SCOPE_AGENT) == 0)
      __builtin_amdgcn_s_sleep(8);
  }
  __syncthreads();

  float h = 0.f;
  for (int j = s0; j < g; ++j) {
    unsigned long long u = __hip_atomic_load(AH + (size_t)j * D_ + d,
                                             __ATOMIC_RELAXED,
                                             __HIP_MEMORY_SCOPE_AGENT);
    union { unsigned long long u; float f2[2]; } pk;
    pk.u = u;
    h = pk.f2[1] + pk.f2[0] * h;
  }

  // ---- replay chunk from LDS with true h_start, write fp32 out ----
  const size_t base = (size_t)row0b * D_ + d;
#pragma unroll 8
  for (int t = 0; t < CHUNK; ++t) {
    const XF v = *(const XF*)(smem + ((size_t)t * D_ + d) * 4);
    const float f = (float)v.f;
    h = f * (float)v.x + (1.f - f) * h;
    out[base + (size_t)t * D_] = h;
  }
}

// ---------------------------------------------------------------------------
extern "C" void kernel_launch(void* const* d_in, const int* in_sizes, int n_in,
                              void* d_out, int out_size, void* d_ws, size_t ws_size,
                              hipStream_t stream) {
  const float* inputs = (const float*)d_in[0];
  const float* mask   = (const float*)d_in[1];
  const float* W_in   = (const float*)d_in[2];
  const float* b_in   = (const float*)d_in[3];
  const float* W_f    = (const float*)d_in[4];
  const float* b_f    = (const float*)d_in[5];
  float* out = (float*)d_out;
  char* ws = (char*)d_ws;

  constexpr size_t WSZ = (size_t)2 * 256 * 256 * 2;                 // 256 KiB
  constexpr size_t AHSZ = (size_t)NBLK * D_ * 8;                    // 1 MiB

  _Float16* Wh2 = (_Float16*)ws;
  unsigned long long* AH = (unsigned long long*)(ws + WSZ);
  int* flags = (int*)(ws + WSZ + AHSZ);

  hipMemsetAsync(flags, 0, NBLK * sizeof(int), stream);
  wconv<<<64, 256, 0, stream>>>(W_in, W_f, Wh2);
  gemm_scan<<<NBLK, 256, 0, stream>>>(inputs, Wh2, b_in, b_f, mask, AH, flags,
                                      out);
}